// Round 1
// baseline (630.421 us; speedup 1.0000x reference)
//
#include <hip/hip_runtime.h>

#define NB 2
#define NN 50000
#define ND 128
#define NE 500000
#define LN_EPS 1e-5f

// ---------------- workspace layout (bytes) ----------------
// agg   : float[NB*NN*ND]   @ 0          (51,200,000)
// deg   : int[NN]           @ 51,200,000 (200,000)
// start : int[NN+1]         @ 51,400,000 (200,004 -> pad)
// cursor: int[NN]           @ 51,600,192 (200,000)
// elist : int[NE]           @ 51,800,192 (2,000,000)
// stats : float[NB*NN*2]    @ 53,800,192 (800,000)
#define AGG_OFF    0
#define DEG_OFF    51200000
#define START_OFF  51400000
#define CURSOR_OFF 51600192
#define ELIST_OFF  51800192
#define STATS_OFF  53800192

__global__ void count_kernel(const int* __restrict__ ei, int* __restrict__ deg) {
    int e = blockIdx.x * blockDim.x + threadIdx.x;
    if (e < NE) {
        atomicAdd(&deg[ei[NE + e]], 1);
    }
}

__global__ void scan_kernel(const int* __restrict__ deg, int* __restrict__ start,
                            int* __restrict__ cursor) {
    __shared__ int part[1024];
    const int t = threadIdx.x;
    const int CH = (NN + 1023) / 1024;  // 49
    const int base = t * CH;
    int s = 0;
    for (int i = 0; i < CH; ++i) {
        int idx = base + i;
        if (idx < NN) s += deg[idx];
    }
    part[t] = s;
    __syncthreads();
    for (int off = 1; off < 1024; off <<= 1) {
        int v = (t >= off) ? part[t - off] : 0;
        __syncthreads();
        part[t] += v;
        __syncthreads();
    }
    int run = (t == 0) ? 0 : part[t - 1];
    for (int i = 0; i < CH; ++i) {
        int idx = base + i;
        if (idx < NN) {
            start[idx] = run;
            cursor[idx] = run;
            run += deg[idx];
        }
    }
    if (t == 1023) start[NN] = part[1023];
}

__global__ void fill_kernel(const int* __restrict__ ei, int* __restrict__ cursor,
                            int* __restrict__ elist) {
    int e = blockIdx.x * blockDim.x + threadIdx.x;
    if (e < NE) {
        int d = ei[NE + e];
        int p = atomicAdd(&cursor[d], 1);
        elist[p] = ei[e];
    }
}

// one wave per (b, n): gather-sum h[b, src, :] over the node's in-edges,
// divide by clamped degree, write agg row.
__global__ void agg_kernel(const float* __restrict__ h, const int* __restrict__ start,
                           const int* __restrict__ elist, float* __restrict__ agg) {
    int wid = (blockIdx.x * blockDim.x + threadIdx.x) >> 6;
    int lane = threadIdx.x & 63;
    if (wid >= NB * NN) return;
    int b = wid / NN;
    int n = wid - b * NN;
    int s0 = start[n];
    int s1 = start[n + 1];
    int d = s1 - s0;
    const float* hb = h + (size_t)b * NN * ND;
    float accx = 0.f, accy = 0.f;
    for (int j0 = 0; j0 < d; j0 += 64) {
        int mye = (j0 + lane < d) ? elist[s0 + j0 + lane] : 0;
        int cnt = (d - j0 < 64) ? (d - j0) : 64;
        for (int jj = 0; jj < cnt; ++jj) {
            int s = __shfl(mye, jj);
            const float2 v = *(const float2*)(hb + (size_t)s * ND + lane * 2);
            accx += v.x;
            accy += v.y;
        }
    }
    float sc = 1.0f / (float)(d > 1 ? d : 1);
    float2 o;
    o.x = accx * sc;
    o.y = accy * sc;
    *(float2*)(agg + (size_t)wid * ND + lane * 2) = o;
}

// thread-per-row fused dual GEMV: y = h@Wself^T + agg@Wmsg^T + bias,
// x = h + relu(y) -> out (pre-norm); per-row mean/rstd -> stats.
__global__ void gemv_kernel(const float* __restrict__ h, const float* __restrict__ agg,
                            const float* __restrict__ Wself, const float* __restrict__ Wmsg,
                            const float* __restrict__ bias, float* __restrict__ out,
                            float* __restrict__ stats) {
    int r = blockIdx.x * blockDim.x + threadIdx.x;
    if (r >= NB * NN) return;
    const float* xrow = h + (size_t)r * ND;
    const float* arow = agg + (size_t)r * ND;
    float* orow = out + (size_t)r * ND;
    float sum = 0.f, sumsq = 0.f;
    for (int oc = 0; oc < 4; ++oc) {
        const int o0 = oc * 32;
        float acc[32];
#pragma unroll
        for (int oo = 0; oo < 32; ++oo) acc[oo] = bias[o0 + oo];
        for (int kc = 0; kc < 8; ++kc) {
            const int k0 = kc * 16;
            float x16[16], a16[16];
#pragma unroll
            for (int q = 0; q < 4; ++q) {
                const float4 xv = *(const float4*)(xrow + k0 + q * 4);
                const float4 av = *(const float4*)(arow + k0 + q * 4);
                x16[q * 4 + 0] = xv.x; x16[q * 4 + 1] = xv.y;
                x16[q * 4 + 2] = xv.z; x16[q * 4 + 3] = xv.w;
                a16[q * 4 + 0] = av.x; a16[q * 4 + 1] = av.y;
                a16[q * 4 + 2] = av.z; a16[q * 4 + 3] = av.w;
            }
#pragma unroll 4
            for (int oo = 0; oo < 32; ++oo) {
                const float* wsp = Wself + (size_t)(o0 + oo) * ND + k0;
                const float* wmp = Wmsg + (size_t)(o0 + oo) * ND + k0;
                float as = 0.f, am = 0.f;
#pragma unroll
                for (int k = 0; k < 16; ++k) {
                    as = fmaf(x16[k], wsp[k], as);
                    am = fmaf(a16[k], wmp[k], am);
                }
                acc[oo] += as + am;
            }
        }
#pragma unroll
        for (int oo = 0; oo < 32; ++oo) {
            float y = acc[oo];
            float xv = xrow[o0 + oo] + (y > 0.f ? y : 0.f);
            orow[o0 + oo] = xv;
            sum += xv;
            sumsq = fmaf(xv, xv, sumsq);
        }
    }
    const float inv = 1.0f / (float)ND;
    float mu = sum * inv;
    float var = sumsq * inv - mu * mu;
    float rstd = rsqrtf(var + LN_EPS);
    stats[2 * r] = mu;
    stats[2 * r + 1] = rstd;
}

__global__ void norm_kernel(float* __restrict__ out, const float* __restrict__ stats,
                            const float* __restrict__ gamma, const float* __restrict__ beta) {
    int i = blockIdx.x * blockDim.x + threadIdx.x;  // float4 index
    const int total = NB * NN * ND / 4;
    if (i >= total) return;
    int r = i >> 5;           // 32 float4 per row
    int o4 = (i & 31) * 4;    // feature offset
    float mu = stats[2 * r];
    float rstd = stats[2 * r + 1];
    float4 v = ((const float4*)out)[i];
    const float4 g = *(const float4*)(gamma + o4);
    const float4 bt = *(const float4*)(beta + o4);
    v.x = (v.x - mu) * rstd * g.x + bt.x;
    v.y = (v.y - mu) * rstd * g.y + bt.y;
    v.z = (v.z - mu) * rstd * g.z + bt.z;
    v.w = (v.w - mu) * rstd * g.w + bt.w;
    ((float4*)out)[i] = v;
}

extern "C" void kernel_launch(void* const* d_in, const int* in_sizes, int n_in,
                              void* d_out, int out_size, void* d_ws, size_t ws_size,
                              hipStream_t stream) {
    const float* h = (const float*)d_in[0];
    const int* ei = (const int*)d_in[1];
    const float* Wself = (const float*)d_in[2];
    const float* Wmsg = (const float*)d_in[3];
    const float* bias = (const float*)d_in[4];
    const float* gamma = (const float*)d_in[5];
    const float* beta = (const float*)d_in[6];
    float* out = (float*)d_out;

    char* ws = (char*)d_ws;
    float* agg = (float*)(ws + AGG_OFF);
    int* deg = (int*)(ws + DEG_OFF);
    int* start = (int*)(ws + START_OFF);
    int* cursor = (int*)(ws + CURSOR_OFF);
    int* elist = (int*)(ws + ELIST_OFF);
    float* stats = (float*)(ws + STATS_OFF);

    hipMemsetAsync(deg, 0, NN * sizeof(int), stream);

    count_kernel<<<(NE + 255) / 256, 256, 0, stream>>>(ei, deg);
    scan_kernel<<<1, 1024, 0, stream>>>(deg, start, cursor);
    fill_kernel<<<(NE + 255) / 256, 256, 0, stream>>>(ei, cursor, elist);

    // one wave per (b, n) row
    int nwaves = NB * NN;
    agg_kernel<<<(nwaves * 64 + 255) / 256, 256, 0, stream>>>(h, start, elist, agg);

    int nrows = NB * NN;
    gemv_kernel<<<(nrows + 255) / 256, 256, 0, stream>>>(h, agg, Wself, Wmsg, bias, out, stats);

    int total4 = NB * NN * ND / 4;
    norm_kernel<<<(total4 + 255) / 256, 256, 0, stream>>>(out, stats, gamma, beta);
}

// Round 2
// 359.141 us; speedup vs baseline: 1.7554x; 1.7554x over previous
//
#include <hip/hip_runtime.h>

#define NB 2
#define NN 50000
#define ND 128
#define NE 500000
#define NM (NB * NN)   // 100000 rows
#define LN_EPS 1e-5f

// ---------------- workspace layout (bytes) ----------------
#define AGG_OFF    0
#define DEG_OFF    51200000
#define START_OFF  51400000
#define CURSOR_OFF 51600192
#define ELIST_OFF  51800192

__global__ void count_kernel(const int* __restrict__ ei, int* __restrict__ deg) {
    int e = blockIdx.x * blockDim.x + threadIdx.x;
    if (e < NE) {
        atomicAdd(&deg[ei[NE + e]], 1);
    }
}

__global__ void scan_kernel(const int* __restrict__ deg, int* __restrict__ start,
                            int* __restrict__ cursor) {
    __shared__ int part[1024];
    const int t = threadIdx.x;
    const int CH = (NN + 1023) / 1024;  // 49
    const int base = t * CH;
    int s = 0;
    for (int i = 0; i < CH; ++i) {
        int idx = base + i;
        if (idx < NN) s += deg[idx];
    }
    part[t] = s;
    __syncthreads();
    for (int off = 1; off < 1024; off <<= 1) {
        int v = (t >= off) ? part[t - off] : 0;
        __syncthreads();
        part[t] += v;
        __syncthreads();
    }
    int run = (t == 0) ? 0 : part[t - 1];
    for (int i = 0; i < CH; ++i) {
        int idx = base + i;
        if (idx < NN) {
            start[idx] = run;
            cursor[idx] = run;
            run += deg[idx];
        }
    }
    if (t == 1023) start[NN] = part[1023];
}

__global__ void fill_kernel(const int* __restrict__ ei, int* __restrict__ cursor,
                            int* __restrict__ elist) {
    int e = blockIdx.x * blockDim.x + threadIdx.x;
    if (e < NE) {
        int d = ei[NE + e];
        int p = atomicAdd(&cursor[d], 1);
        elist[p] = ei[e];
    }
}

// one wave per (b, n): gather-sum h[b, src, :] with float4/lane, two edges
// in flight (half-wave each), divide by clamped degree, write agg row.
__global__ void agg_kernel(const float* __restrict__ h, const int* __restrict__ start,
                           const int* __restrict__ elist, float* __restrict__ agg) {
    int wid = (blockIdx.x * blockDim.x + threadIdx.x) >> 6;
    int lane = threadIdx.x & 63;
    if (wid >= NM) return;
    int b = wid / NN;
    int n = wid - b * NN;
    int s0 = start[n];
    int d = start[n + 1] - s0;
    const int half = lane >> 5;    // 0 or 1
    const int l32 = lane & 31;
    const float* hb = h + (size_t)b * NN * ND;
    float ax = 0.f, ay = 0.f, az = 0.f, aw = 0.f;
    for (int j0 = 0; j0 < d; j0 += 64) {
        int mye = (j0 + lane < d) ? elist[s0 + j0 + lane] : -1;
        int cnt = (d - j0 < 64) ? (d - j0) : 64;
        for (int p = 0; p < cnt; p += 2) {
            int e0 = __shfl(mye, p);
            int e1 = (p + 1 < cnt) ? __shfl(mye, p + 1) : -1;
            int e = half ? e1 : e0;
            if (e >= 0) {
                const float4 v = *(const float4*)(hb + (size_t)e * ND + l32 * 4);
                ax += v.x; ay += v.y; az += v.z; aw += v.w;
            }
        }
    }
    // combine halves (lane <-> lane^32)
    ax += __shfl_xor(ax, 32);
    ay += __shfl_xor(ay, 32);
    az += __shfl_xor(az, 32);
    aw += __shfl_xor(aw, 32);
    if (half == 0) {
        float sc = 1.0f / (float)(d > 1 ? d : 1);
        float4 o;
        o.x = ax * sc; o.y = ay * sc; o.z = az * sc; o.w = aw * sc;
        *(float4*)(agg + (size_t)wid * ND + l32 * 4) = o;
    }
}

// Tiled f32 GEMM with fused bias+residual+ReLU+LayerNorm epilogue.
// C[M,128] = h@Wself^T + agg@Wmsg^T ; out = LN(h + relu(C + bias)) * gamma + beta
// Block tile 128x128, 256 threads (16x16), 8x8 micro-tile, BK=16, K phases: h then agg.
#define BM 128
#define BK 16
#define LROW 132   // 128 + 4 pad

__global__ void fused_gemm_kernel(const float* __restrict__ h, const float* __restrict__ agg,
                                  const float* __restrict__ Wself, const float* __restrict__ Wmsg,
                                  const float* __restrict__ bias, const float* __restrict__ gamma,
                                  const float* __restrict__ beta, float* __restrict__ out) {
    __shared__ float As[BK][LROW];
    __shared__ float Bs[BK][LROW];

    const int t = threadIdx.x;
    const int tx = t & 15;
    const int ty = t >> 4;
    const int tx4 = tx * 4;
    const int ty4 = ty * 4;
    const int row0 = blockIdx.x * BM;

    float acc[8][8];
#pragma unroll
    for (int i = 0; i < 8; ++i)
#pragma unroll
        for (int j = 0; j < 8; ++j) acc[i][j] = 0.f;

#pragma unroll
    for (int ph = 0; ph < 2; ++ph) {
        const float* __restrict__ Asrc = ph ? agg : h;
        const float* __restrict__ W = ph ? Wmsg : Wself;
        for (int kc = 0; kc < 8; ++kc) {
            const int k0 = kc * BK;
            __syncthreads();
            // stage A tile transposed: As[k][row]
#pragma unroll
            for (int s = 0; s < 2; ++s) {
                int f = t + s * 256;
                int r = f >> 2;
                int kk4 = (f & 3) * 4;
                int rg = row0 + r;
                if (rg >= NM) rg = NM - 1;
                const float4 v = *(const float4*)(Asrc + (size_t)rg * ND + k0 + kk4);
                As[kk4 + 0][r] = v.x;
                As[kk4 + 1][r] = v.y;
                As[kk4 + 2][r] = v.z;
                As[kk4 + 3][r] = v.w;
            }
            // stage B tile transposed: Bs[k][n] = W[n][k]
#pragma unroll
            for (int s = 0; s < 2; ++s) {
                int f = t + s * 256;
                int n = f >> 2;
                int kk4 = (f & 3) * 4;
                const float4 v = *(const float4*)(W + (size_t)n * ND + k0 + kk4);
                Bs[kk4 + 0][n] = v.x;
                Bs[kk4 + 1][n] = v.y;
                Bs[kk4 + 2][n] = v.z;
                Bs[kk4 + 3][n] = v.w;
            }
            __syncthreads();
#pragma unroll
            for (int kk = 0; kk < BK; ++kk) {
                const float4 a0 = *(const float4*)(&As[kk][ty4]);
                const float4 a1 = *(const float4*)(&As[kk][ty4 + 64]);
                const float4 b0 = *(const float4*)(&Bs[kk][tx4]);
                const float4 b1 = *(const float4*)(&Bs[kk][tx4 + 64]);
                const float a[8] = {a0.x, a0.y, a0.z, a0.w, a1.x, a1.y, a1.z, a1.w};
                const float b[8] = {b0.x, b0.y, b0.z, b0.w, b1.x, b1.y, b1.z, b1.w};
#pragma unroll
                for (int i = 0; i < 8; ++i)
#pragma unroll
                    for (int j = 0; j < 8; ++j)
                        acc[i][j] = fmaf(a[i], b[j], acc[i][j]);
            }
        }
    }

    // ---------------- fused epilogue ----------------
    const float4 bi0 = *(const float4*)(bias + tx4);
    const float4 bi1 = *(const float4*)(bias + tx4 + 64);
    const float4 g0 = *(const float4*)(gamma + tx4);
    const float4 g1 = *(const float4*)(gamma + tx4 + 64);
    const float4 be0 = *(const float4*)(beta + tx4);
    const float4 be1 = *(const float4*)(beta + tx4 + 64);
    const float bb[8] = {bi0.x, bi0.y, bi0.z, bi0.w, bi1.x, bi1.y, bi1.z, bi1.w};
    const float gg[8] = {g0.x, g0.y, g0.z, g0.w, g1.x, g1.y, g1.z, g1.w};
    const float ee[8] = {be0.x, be0.y, be0.z, be0.w, be1.x, be1.y, be1.z, be1.w};
    const float inv = 1.0f / (float)ND;

#pragma unroll
    for (int i = 0; i < 8; ++i) {
        const int lm = (i < 4) ? (ty4 + i) : (64 + ty4 + i - 4);
        const int rg = row0 + lm;
        const bool valid = rg < NM;
        float4 h0, h1;
        if (valid) {
            h0 = *(const float4*)(h + (size_t)rg * ND + tx4);
            h1 = *(const float4*)(h + (size_t)rg * ND + tx4 + 64);
        } else {
            h0 = make_float4(0.f, 0.f, 0.f, 0.f);
            h1 = h0;
        }
        const float hh[8] = {h0.x, h0.y, h0.z, h0.w, h1.x, h1.y, h1.z, h1.w};
        float x[8];
        float sum = 0.f, sumsq = 0.f;
#pragma unroll
        for (int j = 0; j < 8; ++j) {
            float y = acc[i][j] + bb[j];
            float xv = hh[j] + (y > 0.f ? y : 0.f);
            x[j] = xv;
            sum += xv;
            sumsq = fmaf(xv, xv, sumsq);
        }
        // allreduce across the 16 threads (tx = lane bits 0..3) sharing this row
#pragma unroll
        for (int mask = 1; mask < 16; mask <<= 1) {
            sum += __shfl_xor(sum, mask);
            sumsq += __shfl_xor(sumsq, mask);
        }
        const float mu = sum * inv;
        const float var = sumsq * inv - mu * mu;
        const float rstd = rsqrtf(var + LN_EPS);
        float4 o0, o1;
        o0.x = (x[0] - mu) * rstd * gg[0] + ee[0];
        o0.y = (x[1] - mu) * rstd * gg[1] + ee[1];
        o0.z = (x[2] - mu) * rstd * gg[2] + ee[2];
        o0.w = (x[3] - mu) * rstd * gg[3] + ee[3];
        o1.x = (x[4] - mu) * rstd * gg[4] + ee[4];
        o1.y = (x[5] - mu) * rstd * gg[5] + ee[5];
        o1.z = (x[6] - mu) * rstd * gg[6] + ee[6];
        o1.w = (x[7] - mu) * rstd * gg[7] + ee[7];
        if (valid) {
            *(float4*)(out + (size_t)rg * ND + tx4) = o0;
            *(float4*)(out + (size_t)rg * ND + tx4 + 64) = o1;
        }
    }
}

extern "C" void kernel_launch(void* const* d_in, const int* in_sizes, int n_in,
                              void* d_out, int out_size, void* d_ws, size_t ws_size,
                              hipStream_t stream) {
    const float* h = (const float*)d_in[0];
    const int* ei = (const int*)d_in[1];
    const float* Wself = (const float*)d_in[2];
    const float* Wmsg = (const float*)d_in[3];
    const float* bias = (const float*)d_in[4];
    const float* gamma = (const float*)d_in[5];
    const float* beta = (const float*)d_in[6];
    float* out = (float*)d_out;

    char* ws = (char*)d_ws;
    float* agg = (float*)(ws + AGG_OFF);
    int* deg = (int*)(ws + DEG_OFF);
    int* start = (int*)(ws + START_OFF);
    int* cursor = (int*)(ws + CURSOR_OFF);
    int* elist = (int*)(ws + ELIST_OFF);

    hipMemsetAsync(deg, 0, NN * sizeof(int), stream);

    count_kernel<<<(NE + 255) / 256, 256, 0, stream>>>(ei, deg);
    scan_kernel<<<1, 1024, 0, stream>>>(deg, start, cursor);
    fill_kernel<<<(NE + 255) / 256, 256, 0, stream>>>(ei, cursor, elist);

    int nwaves = NM;
    agg_kernel<<<(nwaves * 64 + 255) / 256, 256, 0, stream>>>(h, start, elist, agg);

    int nblocks = (NM + BM - 1) / BM;  // 782
    fused_gemm_kernel<<<nblocks, 256, 0, stream>>>(h, agg, Wself, Wmsg, bias, gamma, beta, out);
}

// Round 3
// 246.221 us; speedup vs baseline: 2.5604x; 1.4586x over previous
//
#include <hip/hip_runtime.h>

#define NB 2
#define NN 50000
#define ND 128
#define NE 500000
#define NM (NB * NN)   // 100000 rows
#define LN_EPS 1e-5f

// ---------------- workspace layout (bytes) ----------------
#define AGG_OFF    0
#define DEG_OFF    51200000
#define START_OFF  51400000
#define CURSOR_OFF 51600192
#define ELIST_OFF  51800192
#define PART_OFF   53800192

#define SCAN_BLK 512
#define SCAN_NB ((NN + SCAN_BLK - 1) / SCAN_BLK)   // 98

__global__ void count_kernel(const int* __restrict__ ei, int* __restrict__ deg) {
    int e = blockIdx.x * blockDim.x + threadIdx.x;
    if (e < NE) {
        atomicAdd(&deg[ei[NE + e]], 1);
    }
}

// stage 1: per-block sum of deg chunk
__global__ void block_reduce_kernel(const int* __restrict__ deg, int* __restrict__ partials) {
    int i = blockIdx.x * SCAN_BLK + threadIdx.x;
    int v = (i < NN) ? deg[i] : 0;
#pragma unroll
    for (int off = 32; off > 0; off >>= 1) v += __shfl_down(v, off);
    __shared__ int wsum[SCAN_BLK / 64];
    int lane = threadIdx.x & 63;
    int w = threadIdx.x >> 6;
    if (lane == 0) wsum[w] = v;
    __syncthreads();
    if (threadIdx.x == 0) {
        int s = 0;
#pragma unroll
        for (int k = 0; k < SCAN_BLK / 64; ++k) s += wsum[k];
        partials[blockIdx.x] = s;
    }
}

// stage 2: exclusive scan of the SCAN_NB partials (single small block)
__global__ void partial_scan_kernel(int* __restrict__ partials) {
    __shared__ int tmp[128];
    int t = threadIdx.x;
    int v = (t < SCAN_NB) ? partials[t] : 0;
    tmp[t] = v;
    __syncthreads();
    for (int off = 1; off < 128; off <<= 1) {
        int u = (t >= off) ? tmp[t - off] : 0;
        __syncthreads();
        tmp[t] += u;
        __syncthreads();
    }
    if (t < SCAN_NB) partials[t] = tmp[t] - v;   // exclusive
}

// stage 3: per-block exclusive scan + global offset -> start, cursor
__global__ void block_scan_kernel(const int* __restrict__ deg, const int* __restrict__ partials,
                                  int* __restrict__ start, int* __restrict__ cursor) {
    __shared__ int tmp[SCAN_BLK];
    int t = threadIdx.x;
    int i = blockIdx.x * SCAN_BLK + t;
    int v = (i < NN) ? deg[i] : 0;
    tmp[t] = v;
    __syncthreads();
    for (int off = 1; off < SCAN_BLK; off <<= 1) {
        int u = (t >= off) ? tmp[t - off] : 0;
        __syncthreads();
        tmp[t] += u;
        __syncthreads();
    }
    if (i < NN) {
        int excl = tmp[t] - v + partials[blockIdx.x];
        start[i] = excl;
        cursor[i] = excl;
    }
    if (i == 0) start[NN] = NE;   // total edges is a constant
}

__global__ void fill_kernel(const int* __restrict__ ei, int* __restrict__ cursor,
                            int* __restrict__ elist) {
    int e = blockIdx.x * blockDim.x + threadIdx.x;
    if (e < NE) {
        int d = ei[NE + e];
        int p = atomicAdd(&cursor[d], 1);
        elist[p] = ei[e];
    }
}

// one wave per (b, n): gather-sum h[b, src, :] with float4/lane, two edges
// in flight (half-wave each), divide by clamped degree, write agg row.
__global__ void agg_kernel(const float* __restrict__ h, const int* __restrict__ start,
                           const int* __restrict__ elist, float* __restrict__ agg) {
    int wid = (blockIdx.x * blockDim.x + threadIdx.x) >> 6;
    int lane = threadIdx.x & 63;
    if (wid >= NM) return;
    int b = wid / NN;
    int n = wid - b * NN;
    int s0 = start[n];
    int d = start[n + 1] - s0;
    const int half = lane >> 5;    // 0 or 1
    const int l32 = lane & 31;
    const float* hb = h + (size_t)b * NN * ND;
    float ax = 0.f, ay = 0.f, az = 0.f, aw = 0.f;
    for (int j0 = 0; j0 < d; j0 += 64) {
        int mye = (j0 + lane < d) ? elist[s0 + j0 + lane] : -1;
        int cnt = (d - j0 < 64) ? (d - j0) : 64;
        for (int p = 0; p < cnt; p += 2) {
            int e0 = __shfl(mye, p);
            int e1 = (p + 1 < cnt) ? __shfl(mye, p + 1) : -1;
            int e = half ? e1 : e0;
            if (e >= 0) {
                const float4 v = *(const float4*)(hb + (size_t)e * ND + l32 * 4);
                ax += v.x; ay += v.y; az += v.z; aw += v.w;
            }
        }
    }
    ax += __shfl_xor(ax, 32);
    ay += __shfl_xor(ay, 32);
    az += __shfl_xor(az, 32);
    aw += __shfl_xor(aw, 32);
    if (half == 0) {
        float sc = 1.0f / (float)(d > 1 ? d : 1);
        float4 o;
        o.x = ax * sc; o.y = ay * sc; o.z = az * sc; o.w = aw * sc;
        *(float4*)(agg + (size_t)wid * ND + l32 * 4) = o;
    }
}

// Tiled f32 GEMM with fused bias+residual+ReLU+LayerNorm epilogue.
#define BM 128
#define BK 16
#define LROW 132   // 128 + 4 pad

__global__ void fused_gemm_kernel(const float* __restrict__ h, const float* __restrict__ agg,
                                  const float* __restrict__ Wself, const float* __restrict__ Wmsg,
                                  const float* __restrict__ bias, const float* __restrict__ gamma,
                                  const float* __restrict__ beta, float* __restrict__ out) {
    __shared__ float As[BK][LROW];
    __shared__ float Bs[BK][LROW];

    const int t = threadIdx.x;
    const int tx = t & 15;
    const int ty = t >> 4;
    const int tx4 = tx * 4;
    const int ty4 = ty * 4;
    const int row0 = blockIdx.x * BM;

    float acc[8][8];
#pragma unroll
    for (int i = 0; i < 8; ++i)
#pragma unroll
        for (int j = 0; j < 8; ++j) acc[i][j] = 0.f;

#pragma unroll
    for (int ph = 0; ph < 2; ++ph) {
        const float* __restrict__ Asrc = ph ? agg : h;
        const float* __restrict__ W = ph ? Wmsg : Wself;
        for (int kc = 0; kc < 8; ++kc) {
            const int k0 = kc * BK;
            __syncthreads();
#pragma unroll
            for (int s = 0; s < 2; ++s) {
                int f = t + s * 256;
                int r = f >> 2;
                int kk4 = (f & 3) * 4;
                int rg = row0 + r;
                if (rg >= NM) rg = NM - 1;
                const float4 v = *(const float4*)(Asrc + (size_t)rg * ND + k0 + kk4);
                As[kk4 + 0][r] = v.x;
                As[kk4 + 1][r] = v.y;
                As[kk4 + 2][r] = v.z;
                As[kk4 + 3][r] = v.w;
            }
#pragma unroll
            for (int s = 0; s < 2; ++s) {
                int f = t + s * 256;
                int n = f >> 2;
                int kk4 = (f & 3) * 4;
                const float4 v = *(const float4*)(W + (size_t)n * ND + k0 + kk4);
                Bs[kk4 + 0][n] = v.x;
                Bs[kk4 + 1][n] = v.y;
                Bs[kk4 + 2][n] = v.z;
                Bs[kk4 + 3][n] = v.w;
            }
            __syncthreads();
#pragma unroll
            for (int kk = 0; kk < BK; ++kk) {
                const float4 a0 = *(const float4*)(&As[kk][ty4]);
                const float4 a1 = *(const float4*)(&As[kk][ty4 + 64]);
                const float4 b0 = *(const float4*)(&Bs[kk][tx4]);
                const float4 b1 = *(const float4*)(&Bs[kk][tx4 + 64]);
                const float a[8] = {a0.x, a0.y, a0.z, a0.w, a1.x, a1.y, a1.z, a1.w};
                const float b[8] = {b0.x, b0.y, b0.z, b0.w, b1.x, b1.y, b1.z, b1.w};
#pragma unroll
                for (int i = 0; i < 8; ++i)
#pragma unroll
                    for (int j = 0; j < 8; ++j)
                        acc[i][j] = fmaf(a[i], b[j], acc[i][j]);
            }
        }
    }

    const float4 bi0 = *(const float4*)(bias + tx4);
    const float4 bi1 = *(const float4*)(bias + tx4 + 64);
    const float4 g0 = *(const float4*)(gamma + tx4);
    const float4 g1 = *(const float4*)(gamma + tx4 + 64);
    const float4 be0 = *(const float4*)(beta + tx4);
    const float4 be1 = *(const float4*)(beta + tx4 + 64);
    const float bb[8] = {bi0.x, bi0.y, bi0.z, bi0.w, bi1.x, bi1.y, bi1.z, bi1.w};
    const float gg[8] = {g0.x, g0.y, g0.z, g0.w, g1.x, g1.y, g1.z, g1.w};
    const float ee[8] = {be0.x, be0.y, be0.z, be0.w, be1.x, be1.y, be1.z, be1.w};
    const float inv = 1.0f / (float)ND;

#pragma unroll
    for (int i = 0; i < 8; ++i) {
        const int lm = (i < 4) ? (ty4 + i) : (64 + ty4 + i - 4);
        const int rg = row0 + lm;
        const bool valid = rg < NM;
        float4 h0, h1;
        if (valid) {
            h0 = *(const float4*)(h + (size_t)rg * ND + tx4);
            h1 = *(const float4*)(h + (size_t)rg * ND + tx4 + 64);
        } else {
            h0 = make_float4(0.f, 0.f, 0.f, 0.f);
            h1 = h0;
        }
        const float hh[8] = {h0.x, h0.y, h0.z, h0.w, h1.x, h1.y, h1.z, h1.w};
        float x[8];
        float sum = 0.f, sumsq = 0.f;
#pragma unroll
        for (int j = 0; j < 8; ++j) {
            float y = acc[i][j] + bb[j];
            float xv = hh[j] + (y > 0.f ? y : 0.f);
            x[j] = xv;
            sum += xv;
            sumsq = fmaf(xv, xv, sumsq);
        }
#pragma unroll
        for (int mask = 1; mask < 16; mask <<= 1) {
            sum += __shfl_xor(sum, mask);
            sumsq += __shfl_xor(sumsq, mask);
        }
        const float mu = sum * inv;
        const float var = sumsq * inv - mu * mu;
        const float rstd = rsqrtf(var + LN_EPS);
        float4 o0, o1;
        o0.x = (x[0] - mu) * rstd * gg[0] + ee[0];
        o0.y = (x[1] - mu) * rstd * gg[1] + ee[1];
        o0.z = (x[2] - mu) * rstd * gg[2] + ee[2];
        o0.w = (x[3] - mu) * rstd * gg[3] + ee[3];
        o1.x = (x[4] - mu) * rstd * gg[4] + ee[4];
        o1.y = (x[5] - mu) * rstd * gg[5] + ee[5];
        o1.z = (x[6] - mu) * rstd * gg[6] + ee[6];
        o1.w = (x[7] - mu) * rstd * gg[7] + ee[7];
        if (valid) {
            *(float4*)(out + (size_t)rg * ND + tx4) = o0;
            *(float4*)(out + (size_t)rg * ND + tx4 + 64) = o1;
        }
    }
}

extern "C" void kernel_launch(void* const* d_in, const int* in_sizes, int n_in,
                              void* d_out, int out_size, void* d_ws, size_t ws_size,
                              hipStream_t stream) {
    const float* h = (const float*)d_in[0];
    const int* ei = (const int*)d_in[1];
    const float* Wself = (const float*)d_in[2];
    const float* Wmsg = (const float*)d_in[3];
    const float* bias = (const float*)d_in[4];
    const float* gamma = (const float*)d_in[5];
    const float* beta = (const float*)d_in[6];
    float* out = (float*)d_out;

    char* ws = (char*)d_ws;
    float* agg = (float*)(ws + AGG_OFF);
    int* deg = (int*)(ws + DEG_OFF);
    int* start = (int*)(ws + START_OFF);
    int* cursor = (int*)(ws + CURSOR_OFF);
    int* elist = (int*)(ws + ELIST_OFF);
    int* partials = (int*)(ws + PART_OFF);

    hipMemsetAsync(deg, 0, NN * sizeof(int), stream);

    count_kernel<<<(NE + 255) / 256, 256, 0, stream>>>(ei, deg);
    block_reduce_kernel<<<SCAN_NB, SCAN_BLK, 0, stream>>>(deg, partials);
    partial_scan_kernel<<<1, 128, 0, stream>>>(partials);
    block_scan_kernel<<<SCAN_NB, SCAN_BLK, 0, stream>>>(deg, partials, start, cursor);
    fill_kernel<<<(NE + 255) / 256, 256, 0, stream>>>(ei, cursor, elist);

    int nwaves = NM;
    agg_kernel<<<(nwaves * 64 + 255) / 256, 256, 0, stream>>>(h, start, elist, agg);

    int nblocks = (NM + BM - 1) / BM;  // 782
    fused_gemm_kernel<<<nblocks, 256, 0, stream>>>(h, agg, Wself, Wmsg, bias, gamma, beta, out);
}

// Round 4
// 171.314 us; speedup vs baseline: 3.6799x; 1.4372x over previous
//
#include <hip/hip_runtime.h>

#define NB 2
#define NN 50000
#define ND 128
#define NE 500000
#define NM (NB * NN)   // 100000 rows
#define LN_EPS 1e-5f

typedef __attribute__((ext_vector_type(8))) short short8;
typedef __attribute__((ext_vector_type(4))) float f32x4;

// ---------------- workspace layout (bytes) ----------------
// hcat : bf16[NM][256]  (h | agg)      @ 0           (51,200,000)
// wcat : bf16[128][256] (Wself | Wmsg) @ 51,200,000  (65,536)
// deg  : int[NN]                       @ 51,265,536
// start: int[NN+1]                     @ 51,465,536
// curs : int[NN]                       @ 51,665,664
// elist: int[NE]                       @ 51,865,664
// part : int[128]                      @ 53,865,664
#define HCAT_OFF   0
#define WCAT_OFF   51200000
#define DEG_OFF    51265536
#define START_OFF  51465536
#define CURSOR_OFF 51665664
#define ELIST_OFF  51865664
#define PART_OFF   53865664

#define SCAN_BLK 512
#define SCAN_NB ((NN + SCAN_BLK - 1) / SCAN_BLK)   // 98

__device__ __forceinline__ unsigned short f32_to_bf16(float f) {
    unsigned u = __builtin_bit_cast(unsigned, f);
    unsigned r = u + 0x7FFFu + ((u >> 16) & 1u);   // RNE
    return (unsigned short)(r >> 16);
}

__device__ __forceinline__ float bf16_to_f32(unsigned short s) {
    unsigned u = ((unsigned)s) << 16;
    return __builtin_bit_cast(float, u);
}

// ---------------- CSR build ----------------
__global__ void count_kernel(const int* __restrict__ ei, int* __restrict__ deg) {
    int e = blockIdx.x * blockDim.x + threadIdx.x;
    if (e < NE) {
        atomicAdd(&deg[ei[NE + e]], 1);
    }
}

__global__ void block_reduce_kernel(const int* __restrict__ deg, int* __restrict__ partials) {
    int i = blockIdx.x * SCAN_BLK + threadIdx.x;
    int v = (i < NN) ? deg[i] : 0;
#pragma unroll
    for (int off = 32; off > 0; off >>= 1) v += __shfl_down(v, off);
    __shared__ int wsum[SCAN_BLK / 64];
    int lane = threadIdx.x & 63;
    int w = threadIdx.x >> 6;
    if (lane == 0) wsum[w] = v;
    __syncthreads();
    if (threadIdx.x == 0) {
        int s = 0;
#pragma unroll
        for (int k = 0; k < SCAN_BLK / 64; ++k) s += wsum[k];
        partials[blockIdx.x] = s;
    }
}

__global__ void partial_scan_kernel(int* __restrict__ partials) {
    __shared__ int tmp[128];
    int t = threadIdx.x;
    int v = (t < SCAN_NB) ? partials[t] : 0;
    tmp[t] = v;
    __syncthreads();
    for (int off = 1; off < 128; off <<= 1) {
        int u = (t >= off) ? tmp[t - off] : 0;
        __syncthreads();
        tmp[t] += u;
        __syncthreads();
    }
    if (t < SCAN_NB) partials[t] = tmp[t] - v;
}

__global__ void block_scan_kernel(const int* __restrict__ deg, const int* __restrict__ partials,
                                  int* __restrict__ start, int* __restrict__ cursor) {
    __shared__ int tmp[SCAN_BLK];
    int t = threadIdx.x;
    int i = blockIdx.x * SCAN_BLK + t;
    int v = (i < NN) ? deg[i] : 0;
    tmp[t] = v;
    __syncthreads();
    for (int off = 1; off < SCAN_BLK; off <<= 1) {
        int u = (t >= off) ? tmp[t - off] : 0;
        __syncthreads();
        tmp[t] += u;
        __syncthreads();
    }
    if (i < NN) {
        int excl = tmp[t] - v + partials[blockIdx.x];
        start[i] = excl;
        cursor[i] = excl;
    }
    if (i == 0) start[NN] = NE;
}

__global__ void fill_kernel(const int* __restrict__ ei, int* __restrict__ cursor,
                            int* __restrict__ elist) {
    int e = blockIdx.x * blockDim.x + threadIdx.x;
    if (e < NE) {
        int d = ei[NE + e];
        int p = atomicAdd(&cursor[d], 1);
        elist[p] = ei[e];
    }
}

// ---------------- f32 -> bf16 converts ----------------
__global__ void convert_h_kernel(const float* __restrict__ h, unsigned short* __restrict__ hcat) {
    int i = blockIdx.x * blockDim.x + threadIdx.x;   // 8-float chunk id
    if (i >= NM * 16) return;
    int row = i >> 4;
    int c = i & 15;
    const float4 v0 = *(const float4*)(h + (size_t)row * ND + c * 8);
    const float4 v1 = *(const float4*)(h + (size_t)row * ND + c * 8 + 4);
    short8 o;
    o[0] = (short)f32_to_bf16(v0.x); o[1] = (short)f32_to_bf16(v0.y);
    o[2] = (short)f32_to_bf16(v0.z); o[3] = (short)f32_to_bf16(v0.w);
    o[4] = (short)f32_to_bf16(v1.x); o[5] = (short)f32_to_bf16(v1.y);
    o[6] = (short)f32_to_bf16(v1.z); o[7] = (short)f32_to_bf16(v1.w);
    *(short8*)(hcat + (size_t)row * 256 + c * 8) = o;
}

__global__ void convert_w_kernel(const float* __restrict__ Wself, const float* __restrict__ Wmsg,
                                 unsigned short* __restrict__ wcat) {
    int i = blockIdx.x * blockDim.x + threadIdx.x;   // 0 .. 128*32-1
    if (i >= 128 * 32) return;
    int row = i >> 5;
    int c = i & 31;
    const float* src = (c < 16) ? (Wself + (size_t)row * ND + c * 8)
                                : (Wmsg + (size_t)row * ND + (c - 16) * 8);
    short8 o;
#pragma unroll
    for (int j = 0; j < 8; ++j) o[j] = (short)f32_to_bf16(src[j]);
    *(short8*)(wcat + (size_t)row * 256 + c * 8) = o;
}

// ---------------- aggregation (bf16 gather) ----------------
// one wave per (b, n): 4 edges in flight (16 lanes x 16B each), f32 accumulate,
// mean, write bf16 into hcat[row][128:256].
__global__ void agg_kernel(unsigned short* __restrict__ hcat, const int* __restrict__ start,
                           const int* __restrict__ elist) {
    int wid = (blockIdx.x * blockDim.x + threadIdx.x) >> 6;
    int l = threadIdx.x & 63;
    if (wid >= NM) return;
    int b = wid / NN;
    int n = wid - b * NN;
    int s0 = start[n];
    int d = start[n + 1] - s0;
    const int g = l >> 4;     // edge slot 0..3
    const int li = l & 15;    // 8-col chunk
    const size_t bbase = (size_t)b * NN * 256;
    float s[8] = {0.f, 0.f, 0.f, 0.f, 0.f, 0.f, 0.f, 0.f};
    for (int j0 = 0; j0 < d; j0 += 64) {
        int mye = (j0 + l < d) ? elist[s0 + j0 + l] : -1;
        int cnt = (d - j0 < 64) ? (d - j0) : 64;
        for (int p = 0; p < cnt; p += 4) {
            int e = __shfl(mye, p + g);
            if (p + g < cnt) {
                const short8 v = *(const short8*)(hcat + bbase + (size_t)e * 256 + li * 8);
#pragma unroll
                for (int j = 0; j < 8; ++j) s[j] += bf16_to_f32((unsigned short)v[j]);
            }
        }
    }
#pragma unroll
    for (int j = 0; j < 8; ++j) {
        s[j] += __shfl_xor(s[j], 16);
        s[j] += __shfl_xor(s[j], 32);
    }
    if (g == 0) {
        float sc = 1.0f / (float)(d > 1 ? d : 1);
        short8 o;
#pragma unroll
        for (int j = 0; j < 8; ++j) o[j] = (short)f32_to_bf16(s[j] * sc);
        *(short8*)(hcat + (size_t)wid * 256 + 128 + li * 8) = o;
    }
}

// ---------------- MFMA GEMM + fused epilogue ----------------
// C[M,128] = hcat[M,256] @ wcat[128,256]^T ; out = LN(h + relu(C + bias)) * gamma + beta
// Block: 256 threads = 4 waves; wave = 32 rows x 128 cols; no LDS.
#define GBM 128

__global__ void mfma_gemm_kernel(const unsigned short* __restrict__ hcat,
                                 const unsigned short* __restrict__ wcat,
                                 const float* __restrict__ h, const float* __restrict__ bias,
                                 const float* __restrict__ gamma, const float* __restrict__ beta,
                                 float* __restrict__ out) {
    const int t = threadIdx.x;
    const int w = t >> 6;
    const int l = t & 63;
    const int l15 = l & 15;
    const int lk = l >> 4;   // 0..3
    const int row0 = blockIdx.x * GBM + w * 32;

    f32x4 acc[2][8];
#pragma unroll
    for (int i = 0; i < 2; ++i)
#pragma unroll
        for (int j = 0; j < 8; ++j) acc[i][j] = (f32x4){0.f, 0.f, 0.f, 0.f};

    int rA0 = row0 + l15;      if (rA0 >= NM) rA0 = NM - 1;
    int rA1 = row0 + 16 + l15; if (rA1 >= NM) rA1 = NM - 1;
    const unsigned short* pa0 = hcat + (size_t)rA0 * 256 + lk * 8;
    const unsigned short* pa1 = hcat + (size_t)rA1 * 256 + lk * 8;
    const unsigned short* pb = wcat + (size_t)l15 * 256 + lk * 8;

#pragma unroll
    for (int ks = 0; ks < 8; ++ks) {
        const int k0 = ks * 32;
        const short8 a0 = *(const short8*)(pa0 + k0);
        const short8 a1 = *(const short8*)(pa1 + k0);
#pragma unroll
        for (int ct = 0; ct < 8; ++ct) {
            const short8 b = *(const short8*)(pb + ct * 16 * 256 + k0);
            acc[0][ct] = __builtin_amdgcn_mfma_f32_16x16x32_bf16(a0, b, acc[0][ct], 0, 0, 0);
            acc[1][ct] = __builtin_amdgcn_mfma_f32_16x16x32_bf16(a1, b, acc[1][ct], 0, 0, 0);
        }
    }

    // fused epilogue: bias + relu + residual + LayerNorm
    float bb[8], gg[8], ee[8];
#pragma unroll
    for (int ct = 0; ct < 8; ++ct) {
        bb[ct] = bias[ct * 16 + l15];
        gg[ct] = gamma[ct * 16 + l15];
        ee[ct] = beta[ct * 16 + l15];
    }
    const float inv = 1.0f / (float)ND;
#pragma unroll
    for (int rt = 0; rt < 2; ++rt) {
#pragma unroll
        for (int rg = 0; rg < 4; ++rg) {
            const int row = row0 + rt * 16 + lk * 4 + rg;
            const bool valid = row < NM;
            const int rc = valid ? row : NM - 1;
            const float* hrow = h + (size_t)rc * ND;
            float x[8];
            float sum = 0.f, sq = 0.f;
#pragma unroll
            for (int ct = 0; ct < 8; ++ct) {
                float y = acc[rt][ct][rg] + bb[ct];
                float xv = hrow[ct * 16 + l15] + (y > 0.f ? y : 0.f);
                x[ct] = xv;
                sum += xv;
                sq = fmaf(xv, xv, sq);
            }
#pragma unroll
            for (int m = 1; m < 16; m <<= 1) {
                sum += __shfl_xor(sum, m);
                sq += __shfl_xor(sq, m);
            }
            const float mu = sum * inv;
            const float rstd = rsqrtf(sq * inv - mu * mu + LN_EPS);
            if (valid) {
                float* orow = out + (size_t)row * ND;
#pragma unroll
                for (int ct = 0; ct < 8; ++ct)
                    orow[ct * 16 + l15] = (x[ct] - mu) * rstd * gg[ct] + ee[ct];
            }
        }
    }
}

extern "C" void kernel_launch(void* const* d_in, const int* in_sizes, int n_in,
                              void* d_out, int out_size, void* d_ws, size_t ws_size,
                              hipStream_t stream) {
    const float* h = (const float*)d_in[0];
    const int* ei = (const int*)d_in[1];
    const float* Wself = (const float*)d_in[2];
    const float* Wmsg = (const float*)d_in[3];
    const float* bias = (const float*)d_in[4];
    const float* gamma = (const float*)d_in[5];
    const float* beta = (const float*)d_in[6];
    float* out = (float*)d_out;

    char* ws = (char*)d_ws;
    unsigned short* hcat = (unsigned short*)(ws + HCAT_OFF);
    unsigned short* wcat = (unsigned short*)(ws + WCAT_OFF);
    int* deg = (int*)(ws + DEG_OFF);
    int* start = (int*)(ws + START_OFF);
    int* cursor = (int*)(ws + CURSOR_OFF);
    int* elist = (int*)(ws + ELIST_OFF);
    int* partials = (int*)(ws + PART_OFF);

    hipMemsetAsync(deg, 0, NN * sizeof(int), stream);

    count_kernel<<<(NE + 255) / 256, 256, 0, stream>>>(ei, deg);
    block_reduce_kernel<<<SCAN_NB, SCAN_BLK, 0, stream>>>(deg, partials);
    partial_scan_kernel<<<1, 128, 0, stream>>>(partials);
    block_scan_kernel<<<SCAN_NB, SCAN_BLK, 0, stream>>>(deg, partials, start, cursor);
    fill_kernel<<<(NE + 255) / 256, 256, 0, stream>>>(ei, cursor, elist);

    convert_h_kernel<<<(NM * 16 + 255) / 256, 256, 0, stream>>>(h, hcat);
    convert_w_kernel<<<(128 * 32 + 255) / 256, 256, 0, stream>>>(Wself, Wmsg, wcat);

    agg_kernel<<<(NM * 64 + 255) / 256, 256, 0, stream>>>(hcat, start, elist);

    int nblocks = (NM + GBM - 1) / GBM;  // 782
    mfma_gemm_kernel<<<nblocks, 256, 0, stream>>>(hcat, wcat, h, bias, gamma, beta, out);
}